// Round 12
// baseline (547.933 us; speedup 1.0000x reference)
//
#include <hip/hip_runtime.h>

#define NTOK 2048
#define DIM  1024          // K elements; == bytes for fp8
#define OUTD 50257
#define OPAD 50304         // 393*128
#define NCB  393           // column blocks (128 wide)
#define SEGC 12            // slots per (row, colblock) segment
#define TOPK 32
#define RCAP 256           // refine capacity (determinism: nref<=RCAP always)
#define NREF 80            // exact-refine depth (>=5 sigma rank margin vs fp8 coarse noise)
#define THRESH 0.08f
#define NBLK 6288          // gemm grid

typedef float f32x4 __attribute__((ext_vector_type(4)));

// ---- f32 -> OCP e4m3fn, RNE, saturating (hand-rolled: no API risk) -------
__device__ __forceinline__ unsigned int f2e4m3(float f){
    unsigned int u = __float_as_uint(f);
    unsigned int sgn = (u >> 24) & 0x80u;
    int exp = (int)((u >> 23) & 0xFF);
    unsigned int man = u & 0x7FFFFF;
    int e = exp - 127;
    if (e >= 9) return sgn | 0x7E;                 // saturate to 448
    unsigned int full = 0x800000u | man;           // 24-bit significand
    int shift = (e >= -6) ? 20 : 20 + (-6 - e);    // subnormal extra shift
    if (shift >= 24) return sgn;                   // -> 0 (also f32 subnorm/0)
    unsigned int kept = full >> shift;
    unsigned int rem  = full & ((1u << shift) - 1);
    unsigned int half = 1u << (shift - 1);
    if (rem > half || (rem == half && (kept & 1))) kept++;
    if (e >= -6){
        unsigned int ee = (unsigned)(e + 7);
        if (kept >= 16){ kept >>= 1; ee++; }
        if (ee > 15 || (ee == 15 && (kept & 7) > 6)) return sgn | 0x7E;
        return sgn | (ee << 3) | (kept - 8);
    } else {
        if (kept >= 8) return sgn | 0x08;          // rounds up to min normal
        return sgn | kept;                         // subnormal
    }
}
__device__ __forceinline__ unsigned int pack4_e4m3(float a, float b, float c, float d){
    return f2e4m3(a) | (f2e4m3(b) << 8) | (f2e4m3(c) << 16) | (f2e4m3(d) << 24);
}

#define GLDS(gp, lp) __builtin_amdgcn_global_load_lds( \
    (__attribute__((address_space(1))) void*)(gp),     \
    (__attribute__((address_space(3))) void*)(lp), 16, 0, 0)

// ------- kernel 1: x-row L2-normalize, x8 = e4m3(32 * x_hat) --------------
extern "C" __global__ void k_init(const float* __restrict__ x,
                                  unsigned char* __restrict__ x8){
    __shared__ double ls[4];
    const int row = blockIdx.x, t = threadIdx.x;
    float4 v = ((const float4*)(x + (size_t)row * DIM))[t];
    double s = (double)v.x*v.x + (double)v.y*v.y
             + (double)v.z*v.z + (double)v.w*v.w;
    for (int d = 32; d >= 1; d >>= 1) s += __shfl_xor(s, d, 64);
    const int wv = t >> 6, ln = t & 63;
    if (ln == 0) ls[wv] = s;
    __syncthreads();
    double tot = ls[0] + ls[1] + ls[2] + ls[3];
    float sc = (float)(32.0 / fmax(sqrt(tot), 1e-12));
    ((unsigned int*)(x8 + (size_t)row * DIM))[t] =
        pack4_e4m3(v.x*sc, v.y*sc, v.z*sc, v.w*sc);
}

// ------- kernel 2: w8 = e4m3(32 * w_hat); ri64 = 1/max(||w||,eps) ---------
extern "C" __global__ void k_wnorm(const float* __restrict__ w,
                                   unsigned char* __restrict__ w8,
                                   double* __restrict__ ri64){
    __shared__ double ls[4];
    int r = blockIdx.x, t = threadIdx.x;
    if (r < OUTD){
        float4 v = ((const float4*)(w + (size_t)r * DIM))[t];
        double s = (double)v.x*v.x + (double)v.y*v.y
                 + (double)v.z*v.z + (double)v.w*v.w;
        for (int d = 32; d >= 1; d >>= 1) s += __shfl_xor(s, d, 64);
        int wv = t >> 6, ln = t & 63;
        if (ln == 0) ls[wv] = s;
        __syncthreads();
        double tot = ls[0] + ls[1] + ls[2] + ls[3];
        double ri = 1.0 / fmax(sqrt(tot), 1e-12);
        if (t == 0) ri64[r] = ri;
        float sc = (float)(32.0 * ri);
        ((unsigned int*)(w8 + (size_t)r * DIM))[t] =
            pack4_e4m3(v.x*sc, v.y*sc, v.z*sc, v.w*sc);
    } else { // pad rows: zero -> acc 0 -> filtered
        ((unsigned int*)(w8 + (size_t)r * DIM))[t] = 0u;
        if (t == 0) ri64[r] = 0.0;
    }
}

// ------ kernel 3: fp8 MFMA GEMM (4 waves 2x2, 64x64/wave, BK=32, dbuf) ----
// Epilogue: ATOMIC-FREE segmented candidate store + FUSED out-zeroing.
// Zero stores are issued AFTER the last barrier (fire-and-forget, retire
// lazily, hidden under other blocks' compute); kernel-boundary completion
// orders them before k_sel's scatter. This removes the 412MB serial drain
// that k_sel's first __syncthreads (vmcnt(0)) was paying.
#define COMPUTE(b) do { \
  long af_[4], bv_[4]; \
  const char* Ab_ = As[b] + (lk>>1)*2048 + (lk&1)*8; \
  const char* Bb_ = Bs[b] + (lk>>1)*2048 + (lk&1)*8; \
  _Pragma("unroll") \
  for (int m_ = 0; m_ < 4; ++m_) \
    af_[m_] = *(const long*)(Ab_ + (wm*64 + m_*16 + lr)*16); \
  _Pragma("unroll") \
  for (int n_ = 0; n_ < 4; ++n_) \
    bv_[n_] = *(const long*)(Bb_ + (wn*64 + n_*16 + lr)*16); \
  __builtin_amdgcn_s_setprio(1); \
  _Pragma("unroll") \
  for (int m_ = 0; m_ < 4; ++m_) \
    _Pragma("unroll") \
    for (int n_ = 0; n_ < 4; ++n_) \
      acc[m_][n_] = __builtin_amdgcn_mfma_f32_16x16x32_fp8_fp8( \
                        af_[m_], bv_[n_], acc[m_][n_], 0, 0, 0); \
  __builtin_amdgcn_s_setprio(0); \
} while(0)

#define STAGE(b, K0) do { \
  GLDS(x8 + offA + (K0), As[b] + dstOff); \
  GLDS(w8 + offB + (K0), Bs[b] + dstOff); \
} while(0)

extern "C" __global__ __launch_bounds__(256)
void k_gemm(const unsigned char* __restrict__ x8,
            const unsigned char* __restrict__ w8,
            unsigned long long* __restrict__ cpk,
            unsigned char* __restrict__ cnt8,
            float* __restrict__ out){
    __shared__ __align__(16) char As[2][4096];
    __shared__ __align__(16) char Bs[2][4096];
    __shared__ int lcnt[128];
    const int tid = threadIdx.x;

    // bijective chunked XCD remap: 6288 = 8*786
    const int orig  = blockIdx.x;
    const int newid = (orig & 7) * 786 + (orig >> 3);
    const int bm    = (newid & 15) * 128;
    const int cb    = newid >> 4;               // column block 0..392
    const int bn    = cb * 128;

    const int wv = tid >> 6, lane = tid & 63;
    const int wm = wv >> 1,  wn = wv & 1;       // 2x2 waves, 64x64 each
    const int lr = lane & 15, lk = lane >> 4;

    if (tid < 128) lcnt[tid] = 0;

    f32x4 z = {0.f, 0.f, 0.f, 0.f};
    f32x4 acc[4][4];
    for (int m = 0; m < 4; ++m) for (int n = 0; n < 4; ++n) acc[m][n] = z;

    // staging: 256 segs of 16B per matrix per K-step; 1 each (A,B)/thread
    const int srow   = tid & 127;
    const int sh     = tid >> 7;                // 16B-half within BK=32
    const int dstOff = sh*2048 + srow*16;       // pair-subtiled, wave-linear
    const size_t offA = (size_t)(bm + srow)*DIM + sh*16;
    const size_t offB = (size_t)(bn + srow)*DIM + sh*16;

    STAGE(0, 0);
    __syncthreads();                 // buf0 staged; lcnt init visible
    int buf = 0;
    for (int k0 = 32; k0 < DIM; k0 += 32){
        STAGE(buf ^ 1, k0);          // prefetch next K-step
        COMPUTE(buf);                // 8 ds_read_b64 + 16 MFMA
        __syncthreads();
        buf ^= 1;
    }
    COMPUTE(buf);

    // epilogue: cos = acc/1024; append to this block's (row, cb) segments
    const float inv = 1.0f / 1024.0f;
    #pragma unroll
    for (int n = 0; n < 4; ++n){
        int gcol = bn + wn*64 + n*16 + lr;
        bool ok = gcol < OUTD;
        #pragma unroll
        for (int m = 0; m < 4; ++m){
            int lr0 = wm*64 + m*16 + lk*4;        // local row (C/D layout)
            #pragma unroll
            for (int r = 0; r < 4; ++r){
                float sc = acc[m][n][r] * inv;
                if (ok && sc > THRESH){
                    int lrow = lr0 + r;
                    int pos = atomicAdd(&lcnt[lrow], 1);   // LDS atomic only
                    if (pos < SEGC)
                        cpk[((size_t)(bm + lrow)*NCB + cb)*SEGC + pos] =
                            ((unsigned long long)(unsigned)gcol << 32) |
                            (unsigned long long)__float_as_uint(sc);
                }
            }
        }
    }
    __syncthreads();                 // drains cpk stores (few/thread) only
    if (tid < 128)
        cnt8[(size_t)(bm + tid)*NCB + cb] =
            (unsigned char)min(lcnt[tid], SEGC);

    // fused out-zeroing: grid-stride slice, fire-and-forget (no barrier after)
    {
        const size_t n4 = (size_t)NTOK * OUTD / 4;   // 25,731,584 exact
        float4 z4 = make_float4(0.f, 0.f, 0.f, 0.f);
        for (size_t i = (size_t)orig*256 + tid; i < n4; i += (size_t)NBLK*256)
            ((float4*)out)[i] = z4;
    }
}

// -------- kernel 4: select + f64 refine + scatter (zeroing moved to gemm) -
// Determinism: refine SET = {candidates in bins >= bstar} is order-invariant;
// segment contents are set-complete (cap-12 overflow prob ~3e-7/run);
// f64 scores + (score desc, idx asc) sort -> arrival-order independent.
extern "C" __global__ __launch_bounds__(256)
void k_sel(const float* __restrict__ x, const float* __restrict__ w,
           const float* __restrict__ bias,
           const unsigned long long* __restrict__ cpk,
           const unsigned char* __restrict__ cnt8,
           const double* __restrict__ ri64,
           float* __restrict__ out){
    const int row = blockIdx.x, tid = threadIdx.x;
    __shared__ float  xl[DIM];
    __shared__ int    hist[256];
    __shared__ int    bstar, nref;
    __shared__ int    ridx[RCAP];
    __shared__ double rsc[RCAP];
    __shared__ double rdv[RCAP];

    ((float4*)xl)[tid] = ((const float4*)(x + (size_t)row*DIM))[tid];
    hist[tid] = 0;
    if (tid == 0) nref = 0;
    __syncthreads();

    const unsigned char* rc8 = cnt8 + (size_t)row*NCB;
    const unsigned long long* rseg = cpk + (size_t)row*NCB*SEGC;

    // histogram of coarse scores (bins of 7.8e-4 over [0.08, 0.28])
    for (int cb = tid; cb < NCB; cb += 256){
        int c = rc8[cb];
        for (int j = 0; j < c; ++j){
            float s = __uint_as_float((unsigned)(rseg[cb*SEGC + j] & 0xFFFFFFFFu));
            int b = (int)((s - THRESH) * 1280.f);
            b = max(0, min(255, b));
            atomicAdd(&hist[b], 1);
        }
    }
    __syncthreads();
    if (tid == 0){  // smallest bin whose top-cumulative >= NREF
        int cum = 0, b = 255;
        for (; b >= 0; --b){ cum += hist[b]; if (cum >= NREF) break; }
        bstar = b < 0 ? 0 : b;
    }
    __syncthreads();
    const int bs_ = bstar;
    for (int cb = tid; cb < NCB; cb += 256){
        int c = rc8[cb];
        for (int j = 0; j < c; ++j){
            unsigned long long pk = rseg[cb*SEGC + j];
            float s = __uint_as_float((unsigned)(pk & 0xFFFFFFFFu));
            int b = (int)((s - THRESH) * 1280.f);
            b = max(0, min(255, b));
            if (b >= bs_){
                int p = atomicAdd(&nref, 1);
                if (p < RCAP) ridx[p] = (int)(pk >> 32);
            }
        }
    }
    __syncthreads();
    const int nr = min(nref, RCAP);

    // f64 refine: one wave per candidate, float4-vectorized loads
    const int wv = tid >> 6, lane = tid & 63;
    const float4* xl4 = (const float4*)xl;
    for (int q = wv; q < nr; q += 4){
        int col = ridx[q];
        const float4* wr4 = (const float4*)(w + (size_t)col*DIM);
        double s = 0.0;
        #pragma unroll
        for (int u = 0; u < 4; ++u){
            float4 a = xl4[lane + 64*u];
            float4 b = wr4[lane + 64*u];
            s = fma((double)a.x, (double)b.x, s);
            s = fma((double)a.y, (double)b.y, s);
            s = fma((double)a.z, (double)b.z, s);
            s = fma((double)a.w, (double)b.w, s);
        }
        for (int d = 32; d >= 1; d >>= 1) s += __shfl_xor(s, d, 64);
        if (lane == 0){ rdv[q] = s; rsc[q] = s * ri64[col]; }
    }
    __syncthreads();
    if (tid >= nr){ rsc[tid] = -1.0e300; ridx[tid] = 0x7FFFFFFF; rdv[tid] = 0.0; }
    __syncthreads();

    // bitonic sort 256: descending score, ties -> smaller index
    for (int k = 2; k <= RCAP; k <<= 1){
        for (int j = k >> 1; j > 0; j >>= 1){
            int i = tid, ixj = i ^ j;
            if (ixj > i){
                double sa = rsc[i], sb = rsc[ixj];
                int ia = ridx[i], ib = ridx[ixj];
                bool dir = ((i & k) == 0);
                bool pb = (sb > sa) || (sb == sa && ib < ia);
                if (pb == dir){
                    rsc[i] = sb; rsc[ixj] = sa;
                    ridx[i] = ib; ridx[ixj] = ia;
                    double t = rdv[i]; rdv[i] = rdv[ixj]; rdv[ixj] = t;
                }
            }
            __syncthreads();
        }
    }
    if (tid < TOPK && tid < nr){
        int col = ridx[tid];
        out[(size_t)row*OUTD + col] = (float)rdv[tid] + bias[col];
    }
}

// ---------------- launch --------------------------------------------------
extern "C" void kernel_launch(void* const* d_in, const int* in_sizes, int n_in,
                              void* d_out, int out_size, void* d_ws, size_t ws_size,
                              hipStream_t stream){
    const float* x    = (const float*)d_in[0];
    const float* wgt  = (const float*)d_in[1];
    const float* bias = (const float*)d_in[2];
    float* out = (float*)d_out;
    char* ws = (char*)d_ws;

    // workspace carve (~132 MB)
    unsigned char* w8 = (unsigned char*)ws;                         // 51,511,296
    unsigned char* x8 = (unsigned char*)(ws + 51511296);            //  2,097,152
    double* ri64 = (double*)(ws + 53608448);                        //    402,432
    unsigned long long* cpk = (unsigned long long*)(ws + 54010880); // 77,266,944
    unsigned char* cnt8 = (unsigned char*)(ws + 131277824);         //    804,864

    k_init <<<NTOK, 256, 0, stream>>>(x, x8);
    k_wnorm<<<OPAD, 256, 0, stream>>>(wgt, w8, ri64);
    k_gemm <<<NBLK, 256, 0, stream>>>(x8, w8, cpk, cnt8, out);
    k_sel  <<<NTOK, 256, 0, stream>>>(x, wgt, bias, cpk, cnt8, ri64, out);
}

// Round 13
// 529.550 us; speedup vs baseline: 1.0347x; 1.0347x over previous
//
#include <hip/hip_runtime.h>

#define NTOK 2048
#define DIM  1024          // K elements; == bytes for fp8
#define OUTD 50257
#define OPAD 50304         // 393*128
#define NCB  393           // column blocks (128 wide)
#define SEGC 12            // slots per (row, colblock) segment
#define TOPK 32
#define RCAP 256           // refine capacity (determinism: nref<=RCAP always)
#define NREF 80            // exact-refine depth (>=5 sigma rank margin vs fp8 coarse noise)
#define THRESH 0.08f
#define NBLK 6288          // gemm grid

typedef float f32x4 __attribute__((ext_vector_type(4)));

// ---- f32 -> OCP e4m3fn, RNE, saturating (hand-rolled: no API risk) -------
__device__ __forceinline__ unsigned int f2e4m3(float f){
    unsigned int u = __float_as_uint(f);
    unsigned int sgn = (u >> 24) & 0x80u;
    int exp = (int)((u >> 23) & 0xFF);
    unsigned int man = u & 0x7FFFFF;
    int e = exp - 127;
    if (e >= 9) return sgn | 0x7E;                 // saturate to 448
    unsigned int full = 0x800000u | man;           // 24-bit significand
    int shift = (e >= -6) ? 20 : 20 + (-6 - e);    // subnormal extra shift
    if (shift >= 24) return sgn;                   // -> 0 (also f32 subnorm/0)
    unsigned int kept = full >> shift;
    unsigned int rem  = full & ((1u << shift) - 1);
    unsigned int half = 1u << (shift - 1);
    if (rem > half || (rem == half && (kept & 1))) kept++;
    if (e >= -6){
        unsigned int ee = (unsigned)(e + 7);
        if (kept >= 16){ kept >>= 1; ee++; }
        if (ee > 15 || (ee == 15 && (kept & 7) > 6)) return sgn | 0x7E;
        return sgn | (ee << 3) | (kept - 8);
    } else {
        if (kept >= 8) return sgn | 0x08;          // rounds up to min normal
        return sgn | kept;                         // subnormal
    }
}
__device__ __forceinline__ unsigned int pack4_e4m3(float a, float b, float c, float d){
    return f2e4m3(a) | (f2e4m3(b) << 8) | (f2e4m3(c) << 16) | (f2e4m3(d) << 24);
}

#define GLDS(gp, lp) __builtin_amdgcn_global_load_lds( \
    (__attribute__((address_space(1))) void*)(gp),     \
    (__attribute__((address_space(3))) void*)(lp), 16, 0, 0)

// ------- kernel 1: x-row L2-normalize, x8 = e4m3(32 * x_hat) --------------
extern "C" __global__ void k_init(const float* __restrict__ x,
                                  unsigned char* __restrict__ x8){
    __shared__ double ls[4];
    const int row = blockIdx.x, t = threadIdx.x;
    float4 v = ((const float4*)(x + (size_t)row * DIM))[t];
    double s = (double)v.x*v.x + (double)v.y*v.y
             + (double)v.z*v.z + (double)v.w*v.w;
    for (int d = 32; d >= 1; d >>= 1) s += __shfl_xor(s, d, 64);
    const int wv = t >> 6, ln = t & 63;
    if (ln == 0) ls[wv] = s;
    __syncthreads();
    double tot = ls[0] + ls[1] + ls[2] + ls[3];
    float sc = (float)(32.0 / fmax(sqrt(tot), 1e-12));
    ((unsigned int*)(x8 + (size_t)row * DIM))[t] =
        pack4_e4m3(v.x*sc, v.y*sc, v.z*sc, v.w*sc);
}

// ------- kernel 2: w8 = e4m3(32 * w_hat); ri64 = 1/max(||w||,eps) ---------
extern "C" __global__ void k_wnorm(const float* __restrict__ w,
                                   unsigned char* __restrict__ w8,
                                   double* __restrict__ ri64){
    __shared__ double ls[4];
    int r = blockIdx.x, t = threadIdx.x;
    if (r < OUTD){
        float4 v = ((const float4*)(w + (size_t)r * DIM))[t];
        double s = (double)v.x*v.x + (double)v.y*v.y
                 + (double)v.z*v.z + (double)v.w*v.w;
        for (int d = 32; d >= 1; d >>= 1) s += __shfl_xor(s, d, 64);
        int wv = t >> 6, ln = t & 63;
        if (ln == 0) ls[wv] = s;
        __syncthreads();
        double tot = ls[0] + ls[1] + ls[2] + ls[3];
        double ri = 1.0 / fmax(sqrt(tot), 1e-12);
        if (t == 0) ri64[r] = ri;
        float sc = (float)(32.0 * ri);
        ((unsigned int*)(w8 + (size_t)r * DIM))[t] =
            pack4_e4m3(v.x*sc, v.y*sc, v.z*sc, v.w*sc);
    } else { // pad rows: zero -> acc 0 -> filtered
        ((unsigned int*)(w8 + (size_t)r * DIM))[t] = 0u;
        if (t == 0) ri64[r] = 0.0;
    }
}

// ------ kernel 3: fp8 MFMA GEMM (4 waves 2x2, 64x64/wave, BK=32, dbuf) ----
// Out-zeroing AMORTIZED across the K-loop: 1 float4 store/thread/iteration
// for the first 16 iterations — each barrier's vmcnt(0) then waits on ONE
// store whose latency is concurrent with the GLDS loads it already waits
// for (vs R12's tail burst, which serialized 65KB/block at endpgm: +57us).
// Epilogue: ATOMIC-FREE segmented candidate store (LDS counters only).
#define COMPUTE(b) do { \
  long af_[4], bv_[4]; \
  const char* Ab_ = As[b] + (lk>>1)*2048 + (lk&1)*8; \
  const char* Bb_ = Bs[b] + (lk>>1)*2048 + (lk&1)*8; \
  _Pragma("unroll") \
  for (int m_ = 0; m_ < 4; ++m_) \
    af_[m_] = *(const long*)(Ab_ + (wm*64 + m_*16 + lr)*16); \
  _Pragma("unroll") \
  for (int n_ = 0; n_ < 4; ++n_) \
    bv_[n_] = *(const long*)(Bb_ + (wn*64 + n_*16 + lr)*16); \
  __builtin_amdgcn_s_setprio(1); \
  _Pragma("unroll") \
  for (int m_ = 0; m_ < 4; ++m_) \
    _Pragma("unroll") \
    for (int n_ = 0; n_ < 4; ++n_) \
      acc[m_][n_] = __builtin_amdgcn_mfma_f32_16x16x32_fp8_fp8( \
                        af_[m_], bv_[n_], acc[m_][n_], 0, 0, 0); \
  __builtin_amdgcn_s_setprio(0); \
} while(0)

#define STAGE(b, K0) do { \
  GLDS(x8 + offA + (K0), As[b] + dstOff); \
  GLDS(w8 + offB + (K0), Bs[b] + dstOff); \
} while(0)

extern "C" __global__ __launch_bounds__(256)
void k_gemm(const unsigned char* __restrict__ x8,
            const unsigned char* __restrict__ w8,
            unsigned long long* __restrict__ cpk,
            unsigned char* __restrict__ cnt8,
            float* __restrict__ out){
    __shared__ __align__(16) char As[2][4096];
    __shared__ __align__(16) char Bs[2][4096];
    __shared__ int lcnt[128];
    const int tid = threadIdx.x;

    // bijective chunked XCD remap: 6288 = 8*786
    const int orig  = blockIdx.x;
    const int newid = (orig & 7) * 786 + (orig >> 3);
    const int bm    = (newid & 15) * 128;
    const int cb    = newid >> 4;               // column block 0..392
    const int bn    = cb * 128;

    const int wv = tid >> 6, lane = tid & 63;
    const int wm = wv >> 1,  wn = wv & 1;       // 2x2 waves, 64x64 each
    const int lr = lane & 15, lk = lane >> 4;

    if (tid < 128) lcnt[tid] = 0;

    f32x4 z = {0.f, 0.f, 0.f, 0.f};
    f32x4 acc[4][4];
    for (int m = 0; m < 4; ++m) for (int n = 0; n < 4; ++n) acc[m][n] = z;

    // staging: 256 segs of 16B per matrix per K-step; 1 each (A,B)/thread
    const int srow   = tid & 127;
    const int sh     = tid >> 7;                // 16B-half within BK=32
    const int dstOff = sh*2048 + srow*16;       // pair-subtiled, wave-linear
    const size_t offA = (size_t)(bm + srow)*DIM + sh*16;
    const size_t offB = (size_t)(bn + srow)*DIM + sh*16;

    const size_t n4 = (size_t)NTOK * OUTD / 4;  // 25,731,584
    const float4 z4 = make_float4(0.f, 0.f, 0.f, 0.f);

    STAGE(0, 0);
    __syncthreads();                 // buf0 staged; lcnt init visible
    int buf = 0, it = 0;
    for (int k0 = 32; k0 < DIM; k0 += 32){
        STAGE(buf ^ 1, k0);          // prefetch next K-step
        if (it < 16){                // amortized zero slice
            size_t zi = ((size_t)orig*16 + it)*256 + tid;
            if (zi < n4) ((float4*)out)[zi] = z4;
        }
        COMPUTE(buf);                // 8 ds_read_b64 + 16 MFMA
        __syncthreads();
        buf ^= 1; ++it;
    }
    COMPUTE(buf);

    // epilogue: cos = acc/1024; append to this block's (row, cb) segments
    const float inv = 1.0f / 1024.0f;
    #pragma unroll
    for (int n = 0; n < 4; ++n){
        int gcol = bn + wn*64 + n*16 + lr;
        bool ok = gcol < OUTD;
        #pragma unroll
        for (int m = 0; m < 4; ++m){
            int lr0 = wm*64 + m*16 + lk*4;        // local row (C/D layout)
            #pragma unroll
            for (int r = 0; r < 4; ++r){
                float sc = acc[m][n][r] * inv;
                if (ok && sc > THRESH){
                    int lrow = lr0 + r;
                    int pos = atomicAdd(&lcnt[lrow], 1);   // LDS atomic only
                    if (pos < SEGC)
                        cpk[((size_t)(bm + lrow)*NCB + cb)*SEGC + pos] =
                            ((unsigned long long)(unsigned)gcol << 32) |
                            (unsigned long long)__float_as_uint(sc);
                }
            }
        }
    }
    __syncthreads();                 // drains cpk stores (few/thread) only
    if (tid < 128)
        cnt8[(size_t)(bm + tid)*NCB + cb] =
            (unsigned char)min(lcnt[tid], SEGC);
}

// -------- kernel 4: select + f64 refine + scatter (zeroing in gemm) -------
// Determinism: refine SET = {candidates in bins >= bstar} is order-invariant;
// segment contents are set-complete (cap-12 overflow prob ~3e-7/run);
// f64 scores + (score desc, idx asc) sort -> arrival-order independent.
extern "C" __global__ __launch_bounds__(256)
void k_sel(const float* __restrict__ x, const float* __restrict__ w,
           const float* __restrict__ bias,
           const unsigned long long* __restrict__ cpk,
           const unsigned char* __restrict__ cnt8,
           const double* __restrict__ ri64,
           float* __restrict__ out){
    const int row = blockIdx.x, tid = threadIdx.x;
    __shared__ float  xl[DIM];
    __shared__ int    hist[256];
    __shared__ int    bstar, nref;
    __shared__ int    ridx[RCAP];
    __shared__ double rsc[RCAP];
    __shared__ double rdv[RCAP];

    ((float4*)xl)[tid] = ((const float4*)(x + (size_t)row*DIM))[tid];
    hist[tid] = 0;
    if (tid == 0) nref = 0;
    __syncthreads();

    const unsigned char* rc8 = cnt8 + (size_t)row*NCB;
    const unsigned long long* rseg = cpk + (size_t)row*NCB*SEGC;

    // histogram of coarse scores (bins of 7.8e-4 over [0.08, 0.28])
    for (int cb = tid; cb < NCB; cb += 256){
        int c = rc8[cb];
        for (int j = 0; j < c; ++j){
            float s = __uint_as_float((unsigned)(rseg[cb*SEGC + j] & 0xFFFFFFFFu));
            int b = (int)((s - THRESH) * 1280.f);
            b = max(0, min(255, b));
            atomicAdd(&hist[b], 1);
        }
    }
    __syncthreads();
    if (tid == 0){  // smallest bin whose top-cumulative >= NREF
        int cum = 0, b = 255;
        for (; b >= 0; --b){ cum += hist[b]; if (cum >= NREF) break; }
        bstar = b < 0 ? 0 : b;
    }
    __syncthreads();
    const int bs_ = bstar;
    for (int cb = tid; cb < NCB; cb += 256){
        int c = rc8[cb];
        for (int j = 0; j < c; ++j){
            unsigned long long pk = rseg[cb*SEGC + j];
            float s = __uint_as_float((unsigned)(pk & 0xFFFFFFFFu));
            int b = (int)((s - THRESH) * 1280.f);
            b = max(0, min(255, b));
            if (b >= bs_){
                int p = atomicAdd(&nref, 1);
                if (p < RCAP) ridx[p] = (int)(pk >> 32);
            }
        }
    }
    __syncthreads();
    const int nr = min(nref, RCAP);

    // f64 refine: one wave per candidate, float4-vectorized loads
    const int wv = tid >> 6, lane = tid & 63;
    const float4* xl4 = (const float4*)xl;
    for (int q = wv; q < nr; q += 4){
        int col = ridx[q];
        const float4* wr4 = (const float4*)(w + (size_t)col*DIM);
        double s = 0.0;
        #pragma unroll
        for (int u = 0; u < 4; ++u){
            float4 a = xl4[lane + 64*u];
            float4 b = wr4[lane + 64*u];
            s = fma((double)a.x, (double)b.x, s);
            s = fma((double)a.y, (double)b.y, s);
            s = fma((double)a.z, (double)b.z, s);
            s = fma((double)a.w, (double)b.w, s);
        }
        for (int d = 32; d >= 1; d >>= 1) s += __shfl_xor(s, d, 64);
        if (lane == 0){ rdv[q] = s; rsc[q] = s * ri64[col]; }
    }
    __syncthreads();
    if (tid >= nr){ rsc[tid] = -1.0e300; ridx[tid] = 0x7FFFFFFF; rdv[tid] = 0.0; }
    __syncthreads();

    // bitonic sort 256: descending score, ties -> smaller index
    for (int k = 2; k <= RCAP; k <<= 1){
        for (int j = k >> 1; j > 0; j >>= 1){
            int i = tid, ixj = i ^ j;
            if (ixj > i){
                double sa = rsc[i], sb = rsc[ixj];
                int ia = ridx[i], ib = ridx[ixj];
                bool dir = ((i & k) == 0);
                bool pb = (sb > sa) || (sb == sa && ib < ia);
                if (pb == dir){
                    rsc[i] = sb; rsc[ixj] = sa;
                    ridx[i] = ib; ridx[ixj] = ia;
                    double t = rdv[i]; rdv[i] = rdv[ixj]; rdv[ixj] = t;
                }
            }
            __syncthreads();
        }
    }
    if (tid < TOPK && tid < nr){
        int col = ridx[tid];
        out[(size_t)row*OUTD + col] = (float)rdv[tid] + bias[col];
    }
}

// ---------------- launch --------------------------------------------------
extern "C" void kernel_launch(void* const* d_in, const int* in_sizes, int n_in,
                              void* d_out, int out_size, void* d_ws, size_t ws_size,
                              hipStream_t stream){
    const float* x    = (const float*)d_in[0];
    const float* wgt  = (const float*)d_in[1];
    const float* bias = (const float*)d_in[2];
    float* out = (float*)d_out;
    char* ws = (char*)d_ws;

    // workspace carve (~132 MB)
    unsigned char* w8 = (unsigned char*)ws;                         // 51,511,296
    unsigned char* x8 = (unsigned char*)(ws + 51511296);            //  2,097,152
    double* ri64 = (double*)(ws + 53608448);                        //    402,432
    unsigned long long* cpk = (unsigned long long*)(ws + 54010880); // 77,266,944
    unsigned char* cnt8 = (unsigned char*)(ws + 131277824);         //    804,864

    k_init <<<NTOK, 256, 0, stream>>>(x, x8);
    k_wnorm<<<OPAD, 256, 0, stream>>>(wgt, w8, ri64);
    k_gemm <<<NBLK, 256, 0, stream>>>(x8, w8, cpk, cnt8, out);
    k_sel  <<<NTOK, 256, 0, stream>>>(x, wgt, bias, cpk, cnt8, ri64, out);
}